// Round 10
// baseline (247.259 us; speedup 1.0000x reference)
//
#include <hip/hip_runtime.h>
#include <math.h>

#define N_NODES 50000
#define N_EDGES 800000
#define C 128
#define OUTC 64
#define CAP 64               // padded-CSR slots/node; P(deg>64) ~ 3e-20/node
#define NSLICE 8             // XCD count; dst-slice per block-group (blk&7)
#define SLICE_N 6250         // 50000 / 8 exactly

#define BKCAP 104192         // bucket capacity = 407*256 (mean 100k, +12 sigma)
#define BKB 407              // pass-B blocks per slice group
#define FILLB_B (BKB * NSLICE)       // 3256

#define BUCKET_B 3125        // 800000 / 256 exactly
#define CAST_B 3125          // 50000*128/8 / 256 exactly
#define PREPW_B 128          // per layer, 3 layers
#define WLIN_B 32            // 128*64/256

typedef __attribute__((ext_vector_type(8))) short bfrag;   // 8 bf16 (4 VGPRs)
typedef __attribute__((ext_vector_type(4))) float ffrag;   // 4 fp32 acc

__device__ __forceinline__ ushort f2bf(float f) {
    uint u = __builtin_bit_cast(uint, f);
    uint r = (u + 0x7FFFu + ((u >> 16) & 1u)) >> 16;       // RNE
    return (ushort)r;
}
__device__ __forceinline__ float bflo(uint v) {            // low bf16 of packed pair
    uint u = v << 16; return __builtin_bit_cast(float, u);
}
__device__ __forceinline__ float bfhi(uint v) {            // high bf16
    uint u = v & 0xFFFF0000u; return __builtin_bit_cast(float, u);
}

// ---------------------------------------------------------------------------
// Prep pass 1: edge bucketing (single edge scan) + x cast + weight packs.
//   blocks [0, BUCKET_B):  read (dst,src) once; LDS-aggregated append of
//     packed (dloc<<16|src) into bucket[g = dst/6250]. Kills r9's 8x dst
//     re-scan (25.6 MB) — buckets are written as block-contiguous streams.
//   blocks [+CAST_B):      x fp32 -> bf16 (8 ch/thread)
//   blocks [+3*PREPW_B):   [Wl;Wr] pack, layer = sub/128
//   blocks [+WLIN_B):      Wlin pack (K=128, N=64)
// ---------------------------------------------------------------------------

__global__ __launch_bounds__(256) void k_prep1(
    const int* __restrict__ src, const int* __restrict__ dst,
    int* __restrict__ bkcnt, uint* __restrict__ bucket,
    const float4* __restrict__ x4, uint4* __restrict__ xb4,
    const float* __restrict__ Wl0, const float* __restrict__ Wr0,
    const float* __restrict__ Wl1, const float* __restrict__ Wr1,
    const float* __restrict__ Wl2, const float* __restrict__ Wr2,
    const float* __restrict__ Wlin,
    ushort* __restrict__ wp, ushort* __restrict__ wpl) {
    int blk = blockIdx.x;
    if (blk < BUCKET_B) {
        __shared__ int lcnt[NSLICE], lbase[NSLICE];
        int tid = threadIdx.x;
        if (tid < NSLICE) lcnt[tid] = 0;
        __syncthreads();
        int e = blk * 256 + tid;                       // < 800000 exactly
        int d = dst[e];
        int s = src[e];
        int g = d / SLICE_N;                           // magic-mul
        int loc = atomicAdd(&lcnt[g], 1);
        __syncthreads();
        if (tid < NSLICE) lbase[tid] = atomicAdd(&bkcnt[tid], lcnt[tid]);
        __syncthreads();
        int pos = lbase[g] + loc;
        if (pos < BKCAP)
            bucket[g * BKCAP + pos] = ((uint)(d - g * SLICE_N) << 16) | (uint)s;
    } else if (blk < BUCKET_B + CAST_B) {
        int i = (blk - BUCKET_B) * 256 + threadIdx.x;  // < 800000 exactly
        float4 a = x4[i * 2], b = x4[i * 2 + 1];
        uint4 o;
        o.x = (uint)f2bf(a.x) | ((uint)f2bf(a.y) << 16);
        o.y = (uint)f2bf(a.z) | ((uint)f2bf(a.w) << 16);
        o.z = (uint)f2bf(b.x) | ((uint)f2bf(b.y) << 16);
        o.w = (uint)f2bf(b.z) | ((uint)f2bf(b.w) << 16);
        xb4[i] = o;
    } else if (blk < BUCKET_B + CAST_B + 3 * PREPW_B) {
        int sub = blk - (BUCKET_B + CAST_B);
        int layer = sub >> 7;                          // /128
        const float *Wl, *Wr;
        if (layer == 0)      { Wl = Wl0; Wr = Wr0; }
        else if (layer == 1) { Wl = Wl1; Wr = Wr1; }
        else                 { Wl = Wl2; Wr = Wr2; }
        // wp[((nf*8 + ks)*64 + lane)*8 + j] = Wcat[k][n],
        //   n = nf*16 + (lane&15), k = ks*32 + (lane>>4)*8 + j
        int idx = (sub & 127) * 256 + threadIdx.x;     // 0..32767
        int j = idx & 7;
        int lane = (idx >> 3) & 63;
        int ks = (idx >> 9) & 7;
        int nf = idx >> 12;
        int n = nf * 16 + (lane & 15);
        int k = ks * 32 + (lane >> 4) * 8 + j;
        float v = (k < C) ? Wl[k * C + n] : Wr[(k - C) * C + n];
        wp[layer * 32768 + idx] = f2bf(v);
    } else {
        // Wlin pack: K=128 (4 ks), N=64 (4 nf); idx == ((nf*4+ks)*64+lane)*8+j
        int idx = (blk - (BUCKET_B + CAST_B + 3 * PREPW_B)) * 256 + threadIdx.x;
        int j = idx & 7;
        int lane = (idx >> 3) & 63;
        int ks = (idx >> 9) & 3;
        int nf = idx >> 11;                            // 0..3
        int n = nf * 16 + (lane & 15);
        int k = ks * 32 + (lane >> 4) * 8 + j;
        wpl[idx] = f2bf(Wlin[k * OUTC + n]);
    }
}

// ---------------------------------------------------------------------------
// Prep pass 2: slice-local scatter. Group g = blk&7 (XCD g under round-robin)
// drains ONLY bucket g (sequential ~0.4 MB read) into its 0.82 MB cnt/slots
// slice -> atomics + stores fully L2-local, no re-scan.
// ---------------------------------------------------------------------------

__global__ __launch_bounds__(256) void k_prep2(
    const uint* __restrict__ bucket, const int* __restrict__ bkcnt,
    int* __restrict__ cnt, ushort* __restrict__ slots) {
    int g = blockIdx.x & 7;
    int i = (blockIdx.x >> 3) * 256 + threadIdx.x;     // < BKCAP
    int m = bkcnt[g];
    m = (m > BKCAP) ? BKCAP : m;
    if (i < m) {
        uint p = bucket[g * BKCAP + i];
        int d = g * SLICE_N + (int)(p >> 16);
        int pos = atomicAdd(&cnt[d], 1);
        if (pos < CAP) slots[d * CAP + pos] = (ushort)(p & 0xFFFFu);
    }
}

// ---------------------------------------------------------------------------
// Aggregation (padded CSR): wave per node, n <= 64. Lane-group (lane>>4)
// serves neighbor k + grp + {0,4,8,12}; lane loads uint4 (16B, 8 ch) -> one
// VMEM instr gathers 4 rows; 4 loads in flight per iter (16 nbrs; mean deg 16
// -> typically ONE iteration). Tail masked by fmaf weight. shfl_xor(16,32)
// tree-sum; lanes 0-15 write the packed row. FETCH (~105 MB/layer) is the
// compulsory 8-XCD first-touch floor (r8 analysis).
// ---------------------------------------------------------------------------

__global__ __launch_bounds__(256) void k_aggregate(
    const uint* __restrict__ hb, const int* __restrict__ cnt,
    const ushort* __restrict__ slots, uint* __restrict__ aggb) {
    int node = blockIdx.x * 4 + (threadIdx.x >> 6);
    if (node >= N_NODES) return;
    int lane = threadIdx.x & 63;
    int grp = lane >> 4;        // neighbor sub-slot 0..3
    int slot = lane & 15;       // uint4 slot within row
    int n = cnt[node];
    n = (n > CAP) ? CAP : n;
    if (n == 0) {
        if (grp == 0) *(uint4*)&aggb[node * 64 + slot * 4] = make_uint4(0, 0, 0, 0);
        return;
    }
    int sv = slots[node * CAP + ((lane < n) ? lane : 0)];
    float s0 = 0, s1 = 0, s2 = 0, s3 = 0, s4 = 0, s5 = 0, s6 = 0, s7 = 0;
    for (int k = 0; k < n; k += 16) {
        int w0 = k + grp, w1 = k + 4 + grp, w2 = k + 8 + grp, w3 = k + 12 + grp;
        int sA = __shfl(sv, w0), sB = __shfl(sv, w1);
        int sC = __shfl(sv, w2), sD = __shfl(sv, w3);
        float fA = (w0 < n) ? 1.f : 0.f;
        float fB = (w1 < n) ? 1.f : 0.f;
        float fC = (w2 < n) ? 1.f : 0.f;
        float fD = (w3 < n) ? 1.f : 0.f;
        uint4 a = *(const uint4*)&hb[sA * 64 + slot * 4];
        uint4 b = *(const uint4*)&hb[sB * 64 + slot * 4];
        uint4 c = *(const uint4*)&hb[sC * 64 + slot * 4];
        uint4 d = *(const uint4*)&hb[sD * 64 + slot * 4];
        s0 = fmaf(fA, bflo(a.x), s0); s1 = fmaf(fA, bfhi(a.x), s1);
        s2 = fmaf(fA, bflo(a.y), s2); s3 = fmaf(fA, bfhi(a.y), s3);
        s4 = fmaf(fA, bflo(a.z), s4); s5 = fmaf(fA, bfhi(a.z), s5);
        s6 = fmaf(fA, bflo(a.w), s6); s7 = fmaf(fA, bfhi(a.w), s7);
        s0 = fmaf(fB, bflo(b.x), s0); s1 = fmaf(fB, bfhi(b.x), s1);
        s2 = fmaf(fB, bflo(b.y), s2); s3 = fmaf(fB, bfhi(b.y), s3);
        s4 = fmaf(fB, bflo(b.z), s4); s5 = fmaf(fB, bfhi(b.z), s5);
        s6 = fmaf(fB, bflo(b.w), s6); s7 = fmaf(fB, bfhi(b.w), s7);
        s0 = fmaf(fC, bflo(c.x), s0); s1 = fmaf(fC, bfhi(c.x), s1);
        s2 = fmaf(fC, bflo(c.y), s2); s3 = fmaf(fC, bfhi(c.y), s3);
        s4 = fmaf(fC, bflo(c.z), s4); s5 = fmaf(fC, bfhi(c.z), s5);
        s6 = fmaf(fC, bflo(c.w), s6); s7 = fmaf(fC, bfhi(c.w), s7);
        s0 = fmaf(fD, bflo(d.x), s0); s1 = fmaf(fD, bfhi(d.x), s1);
        s2 = fmaf(fD, bflo(d.y), s2); s3 = fmaf(fD, bfhi(d.y), s3);
        s4 = fmaf(fD, bflo(d.z), s4); s5 = fmaf(fD, bfhi(d.z), s5);
        s6 = fmaf(fD, bflo(d.w), s6); s7 = fmaf(fD, bfhi(d.w), s7);
    }
#pragma unroll
    for (int o = 16; o <= 32; o <<= 1) {
        s0 += __shfl_xor(s0, o); s1 += __shfl_xor(s1, o);
        s2 += __shfl_xor(s2, o); s3 += __shfl_xor(s3, o);
        s4 += __shfl_xor(s4, o); s5 += __shfl_xor(s5, o);
        s6 += __shfl_xor(s6, o); s7 += __shfl_xor(s7, o);
    }
    if (grp == 0) {
        float r = 1.0f / (float)n;      // == 1/max(cnt,1), n>=1 here
        uint4 o4;
        o4.x = (uint)f2bf(s0 * r) | ((uint)f2bf(s1 * r) << 16);
        o4.y = (uint)f2bf(s2 * r) | ((uint)f2bf(s3 * r) << 16);
        o4.z = (uint)f2bf(s4 * r) | ((uint)f2bf(s5 * r) << 16);
        o4.w = (uint)f2bf(s6 * r) | ((uint)f2bf(s7 * r) << 16);
        *(uint4*)&aggb[node * 64 + slot * 4] = o4;
    }
}

// ---------------------------------------------------------------------------
// MFMA GEMM (layers 0,1): out = relu([mean||h] @ Wcat + bl). M-tile 64,
// N=128, K=256; 4 waves (wm,wn); 2x4 16x16 frags/wave. A in LDS with XOR
// chunk swizzle; B fragment-linear from global. out may alias mean/h.
// ---------------------------------------------------------------------------

__global__ __launch_bounds__(256) void k_mm_mfma(
    const ushort* mean_b, const ushort* h_b,
    const ushort* __restrict__ Wp, const float* __restrict__ bl,
    ushort* out_b) {
    __shared__ __align__(16) ushort A[64 * 256];

    const int t = threadIdx.x;
    const int node0 = blockIdx.x * 64;

    {
        int r = t >> 2;
        int node = node0 + r;
        int cg = (t & 3) * 8;
        for (int i = 0; i < 8; ++i) {
            int c = cg + i;                       // chunk = 8 bf16 = 16B
            uint4 v = make_uint4(0u, 0u, 0u, 0u);
            if (node < N_NODES) {
                int kk = c * 8;
                const ushort* sp = (kk < C) ? &mean_b[node * C + kk]
                                            : &h_b[node * C + (kk - C)];
                v = *(const uint4*)sp;
            }
            int cs = c ^ (r & 7);
            *(uint4*)&A[r * 256 + cs * 8] = v;
        }
    }
    __syncthreads();

    const int w = t >> 6, lane = t & 63;
    const int wm = w >> 1, wn = w & 1;
    const int lg = lane >> 4, lr = lane & 15;

    ffrag acc[2][4];
#pragma unroll
    for (int im = 0; im < 2; ++im)
#pragma unroll
        for (int in = 0; in < 4; ++in) acc[im][in] = (ffrag)0.f;

#pragma unroll 2
    for (int ks = 0; ks < 8; ++ks) {
        bfrag a[2];
#pragma unroll
        for (int im = 0; im < 2; ++im) {
            int r = wm * 32 + im * 16 + lr;
            int c = ks * 4 + lg;
            int cs = c ^ (r & 7);
            a[im] = *(const bfrag*)&A[r * 256 + cs * 8];
        }
        bfrag b[4];
#pragma unroll
        for (int in = 0; in < 4; ++in) {
            int nf = wn * 4 + in;
            b[in] = *(const bfrag*)&Wp[(((nf * 8) + ks) * 64 + lane) * 8];
        }
#pragma unroll
        for (int im = 0; im < 2; ++im)
#pragma unroll
            for (int in = 0; in < 4; ++in)
                acc[im][in] = __builtin_amdgcn_mfma_f32_16x16x32_bf16(
                    a[im], b[in], acc[im][in], 0, 0, 0);
    }

#pragma unroll
    for (int im = 0; im < 2; ++im) {
#pragma unroll
        for (int in = 0; in < 4; ++in) {
            int ch = wn * 64 + in * 16 + lr;
            float bias = bl[ch];
#pragma unroll
            for (int r = 0; r < 4; ++r) {
                int node = node0 + wm * 32 + im * 16 + lg * 4 + r;
                if (node < N_NODES) {
                    float v = acc[im][in][r] + bias;
                    v = (v > 0.f) ? v : 0.f;
                    out_b[node * C + ch] = f2bf(v);
                }
            }
        }
    }
}

// ---------------------------------------------------------------------------
// Fused layer-2 GEMM + final projection + log_softmax (see r9 notes).
// ---------------------------------------------------------------------------

__global__ __launch_bounds__(256) void k_mm_out(
    const ushort* mean_b, const ushort* h_b,
    const ushort* __restrict__ Wp, const float* __restrict__ bl,
    const ushort* __restrict__ Wpl, const float* __restrict__ blin,
    float* __restrict__ out) {
    __shared__ __align__(16) ushort A[64 * 256];

    const int t = threadIdx.x;
    const int node0 = blockIdx.x * 64;

    {
        int r = t >> 2;
        int node = node0 + r;
        int cg = (t & 3) * 8;
        for (int i = 0; i < 8; ++i) {
            int c = cg + i;
            uint4 v = make_uint4(0u, 0u, 0u, 0u);
            if (node < N_NODES) {
                int kk = c * 8;
                const ushort* sp = (kk < C) ? &mean_b[node * C + kk]
                                            : &h_b[node * C + (kk - C)];
                v = *(const uint4*)sp;
            }
            int cs = c ^ (r & 7);
            *(uint4*)&A[r * 256 + cs * 8] = v;
        }
    }
    __syncthreads();

    const int w = t >> 6, lane = t & 63;
    const int wm = w >> 1, wn = w & 1;
    const int lg = lane >> 4, lr = lane & 15;

    ffrag acc[2][4];
#pragma unroll
    for (int im = 0; im < 2; ++im)
#pragma unroll
        for (int in = 0; in < 4; ++in) acc[im][in] = (ffrag)0.f;

#pragma unroll 2
    for (int ks = 0; ks < 8; ++ks) {
        bfrag a[2];
#pragma unroll
        for (int im = 0; im < 2; ++im) {
            int r = wm * 32 + im * 16 + lr;
            int c = ks * 4 + lg;
            int cs = c ^ (r & 7);
            a[im] = *(const bfrag*)&A[r * 256 + cs * 8];
        }
        bfrag b[4];
#pragma unroll
        for (int in = 0; in < 4; ++in) {
            int nf = wn * 4 + in;
            b[in] = *(const bfrag*)&Wp[(((nf * 8) + ks) * 64 + lane) * 8];
        }
#pragma unroll
        for (int im = 0; im < 2; ++im)
#pragma unroll
            for (int in = 0; in < 4; ++in)
                acc[im][in] = __builtin_amdgcn_mfma_f32_16x16x32_bf16(
                    a[im], b[in], acc[im][in], 0, 0, 0);
    }

    // --- h3 -> LDS (alias A; all waves are done reading A)
    __syncthreads();
    ushort* H = A;          // [64 rows][128 bf16], chunk cs2 = c ^ (row&7)
#pragma unroll
    for (int im = 0; im < 2; ++im) {
#pragma unroll
        for (int in = 0; in < 4; ++in) {
            int ch = wn * 64 + in * 16 + lr;
            float bias = bl[ch];
            int cfull = ch >> 3;            // chunk 0..15
            int cb = ch & 7;
#pragma unroll
            for (int r = 0; r < 4; ++r) {
                int row = wm * 32 + im * 16 + lg * 4 + r;
                float v = acc[im][in][r] + bias;
                v = (v > 0.f) ? v : 0.f;
                H[row * 128 + (cfull ^ (row & 7)) * 8 + cb] = f2bf(v);
            }
        }
    }
    __syncthreads();

    // --- second GEMM: wave w -> rows w*16..w*16+15, all 64 out-ch
    ffrag acc2[4];
#pragma unroll
    for (int in2 = 0; in2 < 4; ++in2) acc2[in2] = (ffrag)0.f;
#pragma unroll
    for (int ks = 0; ks < 4; ++ks) {
        int row = w * 16 + lr;
        int c2 = ks * 4 + lg;
        bfrag a2 = *(const bfrag*)&H[row * 128 + (c2 ^ (row & 7)) * 8];
#pragma unroll
        for (int in2 = 0; in2 < 4; ++in2) {
            bfrag b2 = *(const bfrag*)&Wpl[(((in2 * 4) + ks) * 64 + lane) * 8];
            acc2[in2] = __builtin_amdgcn_mfma_f32_16x16x32_bf16(
                a2, b2, acc2[in2], 0, 0, 0);
        }
    }

    // --- bias + per-node log_softmax (node = node0 + w*16 + lg*4 + r)
    float bv0 = blin[lr], bv1 = blin[16 + lr], bv2 = blin[32 + lr],
          bv3 = blin[48 + lr];
#pragma unroll
    for (int r = 0; r < 4; ++r) {
        int node = node0 + w * 16 + lg * 4 + r;
        float L0 = acc2[0][r] + bv0, L1 = acc2[1][r] + bv1;
        float L2 = acc2[2][r] + bv2, L3 = acc2[3][r] + bv3;
        float m = fmaxf(fmaxf(L0, L1), fmaxf(L2, L3));
#pragma unroll
        for (int o = 1; o < 16; o <<= 1) m = fmaxf(m, __shfl_xor(m, o));
        float s = __expf(L0 - m) + __expf(L1 - m) + __expf(L2 - m) +
                  __expf(L3 - m);
#pragma unroll
        for (int o = 1; o < 16; o <<= 1) s += __shfl_xor(s, o);
        float ls = __logf(s) + m;
        if (node < N_NODES) {
            out[node * OUTC + lr]      = L0 - ls;
            out[node * OUTC + 16 + lr] = L1 - ls;
            out[node * OUTC + 32 + lr] = L2 - ls;
            out[node * OUTC + 48 + lr] = L3 - ls;
        }
    }
}

// ---------------------------------------------------------------------------

extern "C" void kernel_launch(void* const* d_in, const int* in_sizes, int n_in,
                              void* d_out, int out_size, void* d_ws,
                              size_t ws_size, hipStream_t stream) {
    const float* x = (const float*)d_in[0];
    const int* ei = (const int*)d_in[1];
    const int* src = ei;
    const int* dst = ei + N_EDGES;
    const float* Wl0 = (const float*)d_in[2];
    const float* bl0 = (const float*)d_in[3];
    const float* Wr0 = (const float*)d_in[4];
    const float* Wl1 = (const float*)d_in[5];
    const float* bl1 = (const float*)d_in[6];
    const float* Wr1 = (const float*)d_in[7];
    const float* Wl2 = (const float*)d_in[8];
    const float* bl2 = (const float*)d_in[9];
    const float* Wr2 = (const float*)d_in[10];
    const float* Wlin = (const float*)d_in[11];
    const float* blin = (const float*)d_in[12];

    // workspace layout (all 16B-aligned)
    int* cnt = (int*)d_ws;                          // 50000 ints
    int* bkcnt = cnt + N_NODES;                     // 8 ints (zeroed with cnt)
    uint* bucket = (uint*)(bkcnt + 8);              // 8*BKCAP uints (3.33 MB)
    ushort* slots = (ushort*)(bucket + (size_t)NSLICE * BKCAP);  // 6.4 MB
    uint* xb = (uint*)(slots + (size_t)N_NODES * CAP);  // N*64 (12.8 MB)
    uint* bufA = xb + (size_t)N_NODES * 64;         // 12.8 MB
    uint* bufB = bufA + (size_t)N_NODES * 64;       // 12.8 MB
    ushort* wp = (ushort*)(bufB + (size_t)N_NODES * 64);  // 3*32768
    ushort* wpl = wp + 3 * 32768;                   // 8192

    hipMemsetAsync(cnt, 0, (size_t)(N_NODES + 8) * sizeof(int), stream);

    k_prep1<<<BUCKET_B + CAST_B + 3 * PREPW_B + WLIN_B, 256, 0, stream>>>(
        src, dst, bkcnt, bucket, (const float4*)x, (uint4*)xb,
        Wl0, Wr0, Wl1, Wr1, Wl2, Wr2, Wlin, wp, wpl);

    k_prep2<<<FILLB_B, 256, 0, stream>>>(bucket, bkcnt, cnt, slots);

    const int AGG_GRID = (N_NODES + 3) / 4;
    const int MM_GRID = (N_NODES + 63) / 64;

    k_aggregate<<<AGG_GRID, 256, 0, stream>>>(xb, cnt, slots, bufA);
    k_mm_mfma<<<MM_GRID, 256, 0, stream>>>((const ushort*)bufA, (const ushort*)xb,
                                           wp, bl0, (ushort*)bufA);

    k_aggregate<<<AGG_GRID, 256, 0, stream>>>(bufA, cnt, slots, bufB);
    k_mm_mfma<<<MM_GRID, 256, 0, stream>>>((const ushort*)bufB, (const ushort*)bufA,
                                           wp + 32768, bl1, (ushort*)bufB);

    k_aggregate<<<AGG_GRID, 256, 0, stream>>>(bufB, cnt, slots, bufA);
    k_mm_out<<<MM_GRID, 256, 0, stream>>>((const ushort*)bufA, (const ushort*)bufB,
                                          wp + 65536, bl2, wpl, blin,
                                          (float*)d_out);
}

// Round 11
// 204.918 us; speedup vs baseline: 1.2066x; 1.2066x over previous
//
#include <hip/hip_runtime.h>
#include <math.h>

#define N_NODES 50000
#define N_EDGES 800000
#define C 128
#define OUTC 64
#define CAP 64               // padded-CSR slots/node; P(deg>64) ~ 3e-20/node
#define NSLICE 8             // XCD count; dst-slice per block-group (blk&7)
#define SLICE_N 6250         // 50000 / 8 exactly

#define FILL_CH 3125         // edge chunks: 800000 / 256 exactly
#define FILLG_B (FILL_CH * NSLICE)   // 25000 fill blocks (8 groups)
#define CAST_B 3125          // 50000*128/8 / 256 exactly
#define PREPW_B 128          // per layer, 3 layers
#define WLIN_B 32            // 128*64/256

typedef __attribute__((ext_vector_type(8))) short bfrag;   // 8 bf16 (4 VGPRs)
typedef __attribute__((ext_vector_type(4))) float ffrag;   // 4 fp32 acc

__device__ __forceinline__ ushort f2bf(float f) {
    uint u = __builtin_bit_cast(uint, f);
    uint r = (u + 0x7FFFu + ((u >> 16) & 1u)) >> 16;       // RNE
    return (ushort)r;
}
__device__ __forceinline__ float bflo(uint v) {            // low bf16 of packed pair
    uint u = v << 16; return __builtin_bit_cast(float, u);
}
__device__ __forceinline__ float bfhi(uint v) {            // high bf16
    uint u = v & 0xFFFF0000u; return __builtin_bit_cast(float, u);
}

// ---------------------------------------------------------------------------
// Mega prep kernel (r9 form — r10's two-pass bucket variant regressed on the
// 8-counter atomic line ping-pong; single-pass XCD-sliced scatter is the
// measured scatter floor ~45 us).
//   blocks [0, FILLG_B):   XCD-sliced padded-CSR fill (group g = blk&7)
//   blocks [+CAST_B):      x fp32 -> bf16 (8 ch/thread)
//   blocks [+3*PREPW_B):   [Wl;Wr] pack, layer = sub/128
//   blocks [+WLIN_B):      Wlin pack (K=128, N=64)
// ---------------------------------------------------------------------------

__global__ __launch_bounds__(256) void k_prep_mega(
    const int* __restrict__ src, const int* __restrict__ dst,
    int* __restrict__ cnt, ushort* __restrict__ slots,
    const float4* __restrict__ x4, uint4* __restrict__ xb4,
    const float* __restrict__ Wl0, const float* __restrict__ Wr0,
    const float* __restrict__ Wl1, const float* __restrict__ Wr1,
    const float* __restrict__ Wl2, const float* __restrict__ Wr2,
    const float* __restrict__ Wlin,
    ushort* __restrict__ wp, ushort* __restrict__ wpl) {
    int blk = blockIdx.x;
    if (blk < FILLG_B) {
        int grp = blk & 7;                             // target dst slice / XCD
        int e = (blk >> 3) * 256 + threadIdx.x;        // < 800000 exactly
        int d = dst[e];
        if ((unsigned)(d - grp * SLICE_N) < (unsigned)SLICE_N) {
            int pos = atomicAdd(&cnt[d], 1);
            if (pos < CAP) slots[d * CAP + pos] = (ushort)src[e];
        }
    } else if (blk < FILLG_B + CAST_B) {
        int i = (blk - FILLG_B) * 256 + threadIdx.x;   // < 800000 exactly
        float4 a = x4[i * 2], b = x4[i * 2 + 1];
        uint4 o;
        o.x = (uint)f2bf(a.x) | ((uint)f2bf(a.y) << 16);
        o.y = (uint)f2bf(a.z) | ((uint)f2bf(a.w) << 16);
        o.z = (uint)f2bf(b.x) | ((uint)f2bf(b.y) << 16);
        o.w = (uint)f2bf(b.z) | ((uint)f2bf(b.w) << 16);
        xb4[i] = o;
    } else if (blk < FILLG_B + CAST_B + 3 * PREPW_B) {
        int sub = blk - (FILLG_B + CAST_B);
        int layer = sub >> 7;                          // /128
        const float *Wl, *Wr;
        if (layer == 0)      { Wl = Wl0; Wr = Wr0; }
        else if (layer == 1) { Wl = Wl1; Wr = Wr1; }
        else                 { Wl = Wl2; Wr = Wr2; }
        // wp[((nf*8 + ks)*64 + lane)*8 + j] = Wcat[k][n],
        //   n = nf*16 + (lane&15), k = ks*32 + (lane>>4)*8 + j
        int idx = (sub & 127) * 256 + threadIdx.x;     // 0..32767
        int j = idx & 7;
        int lane = (idx >> 3) & 63;
        int ks = (idx >> 9) & 7;
        int nf = idx >> 12;
        int n = nf * 16 + (lane & 15);
        int k = ks * 32 + (lane >> 4) * 8 + j;
        float v = (k < C) ? Wl[k * C + n] : Wr[(k - C) * C + n];
        wp[layer * 32768 + idx] = f2bf(v);
    } else {
        // Wlin pack: K=128 (4 ks), N=64 (4 nf); idx == ((nf*4+ks)*64+lane)*8+j
        int idx = (blk - (FILLG_B + CAST_B + 3 * PREPW_B)) * 256 + threadIdx.x;
        int j = idx & 7;
        int lane = (idx >> 3) & 63;
        int ks = (idx >> 9) & 3;
        int nf = idx >> 11;                            // 0..3
        int n = nf * 16 + (lane & 15);
        int k = ks * 32 + (lane >> 4) * 8 + j;
        wpl[idx] = f2bf(Wlin[k * OUTC + n]);
    }
}

// ---------------------------------------------------------------------------
// Fused SAGE layer v2: 1024 threads = 16 waves, block = 64 nodes.
// Gather: wave w owns rows w*4..w*4+3, ONE node per pass (proven uint4
// lane-group gather, 4 loads in flight); reduced row written by lanes 0-15
// as one uint4 = one swizzled 16B chunk (2-way LDS aliasing = free).
// vs r4's failed fusion: 4 nodes/wave not 16, and 2 blocks/CU
// (__launch_bounds__(1024,8)) so one block's MFMA overlaps the other's
// gather. out_b must NOT alias hb (other blocks still gather from hb).
// ---------------------------------------------------------------------------

__device__ __forceinline__ void sage_gather_stage(
    ushort* A, const uint* __restrict__ hb, const int* __restrict__ cnt,
    const ushort* __restrict__ slots, int node0, int w, int lane) {
    const int grp = lane >> 4;
    const int slot = lane & 15;
    for (int rr = 0; rr < 4; ++rr) {
        int r = (w << 2) | rr;
        int node = node0 + r;
        int n = 0;
        uint4 hv = make_uint4(0u, 0u, 0u, 0u);
        if (node < N_NODES) {
            n = cnt[node];
            n = (n > CAP) ? CAP : n;
            if (grp == 0) hv = *(const uint4*)&hb[node * 64 + slot * 4];
        }
        float s0 = 0, s1 = 0, s2 = 0, s3 = 0, s4 = 0, s5 = 0, s6 = 0, s7 = 0;
        if (n > 0) {
            int sv = slots[node * CAP + ((lane < n) ? lane : 0)];
            for (int k = 0; k < n; k += 16) {
                int w0 = k + grp, w1 = k + 4 + grp;
                int w2 = k + 8 + grp, w3 = k + 12 + grp;
                int sA = __shfl(sv, w0), sB = __shfl(sv, w1);
                int sC = __shfl(sv, w2), sD = __shfl(sv, w3);
                float fA = (w0 < n) ? 1.f : 0.f;
                float fB = (w1 < n) ? 1.f : 0.f;
                float fC = (w2 < n) ? 1.f : 0.f;
                float fD = (w3 < n) ? 1.f : 0.f;
                uint4 a = *(const uint4*)&hb[sA * 64 + slot * 4];
                uint4 b = *(const uint4*)&hb[sB * 64 + slot * 4];
                uint4 c = *(const uint4*)&hb[sC * 64 + slot * 4];
                uint4 d = *(const uint4*)&hb[sD * 64 + slot * 4];
                s0 = fmaf(fA, bflo(a.x), s0); s1 = fmaf(fA, bfhi(a.x), s1);
                s2 = fmaf(fA, bflo(a.y), s2); s3 = fmaf(fA, bfhi(a.y), s3);
                s4 = fmaf(fA, bflo(a.z), s4); s5 = fmaf(fA, bfhi(a.z), s5);
                s6 = fmaf(fA, bflo(a.w), s6); s7 = fmaf(fA, bfhi(a.w), s7);
                s0 = fmaf(fB, bflo(b.x), s0); s1 = fmaf(fB, bfhi(b.x), s1);
                s2 = fmaf(fB, bflo(b.y), s2); s3 = fmaf(fB, bfhi(b.y), s3);
                s4 = fmaf(fB, bflo(b.z), s4); s5 = fmaf(fB, bfhi(b.z), s5);
                s6 = fmaf(fB, bflo(b.w), s6); s7 = fmaf(fB, bfhi(b.w), s7);
                s0 = fmaf(fC, bflo(c.x), s0); s1 = fmaf(fC, bfhi(c.x), s1);
                s2 = fmaf(fC, bflo(c.y), s2); s3 = fmaf(fC, bfhi(c.y), s3);
                s4 = fmaf(fC, bflo(c.z), s4); s5 = fmaf(fC, bfhi(c.z), s5);
                s6 = fmaf(fC, bflo(c.w), s6); s7 = fmaf(fC, bfhi(c.w), s7);
                s0 = fmaf(fD, bflo(d.x), s0); s1 = fmaf(fD, bfhi(d.x), s1);
                s2 = fmaf(fD, bflo(d.y), s2); s3 = fmaf(fD, bfhi(d.y), s3);
                s4 = fmaf(fD, bflo(d.z), s4); s5 = fmaf(fD, bfhi(d.z), s5);
                s6 = fmaf(fD, bflo(d.w), s6); s7 = fmaf(fD, bfhi(d.w), s7);
            }
        }
#pragma unroll
        for (int o = 16; o <= 32; o <<= 1) {
            s0 += __shfl_xor(s0, o); s1 += __shfl_xor(s1, o);
            s2 += __shfl_xor(s2, o); s3 += __shfl_xor(s3, o);
            s4 += __shfl_xor(s4, o); s5 += __shfl_xor(s5, o);
            s6 += __shfl_xor(s6, o); s7 += __shfl_xor(s7, o);
        }
        if (grp == 0) {
            float rd = (n > 0) ? 1.0f / (float)n : 0.f;
            uint4 o4;
            o4.x = (uint)f2bf(s0 * rd) | ((uint)f2bf(s1 * rd) << 16);
            o4.y = (uint)f2bf(s2 * rd) | ((uint)f2bf(s3 * rd) << 16);
            o4.z = (uint)f2bf(s4 * rd) | ((uint)f2bf(s5 * rd) << 16);
            o4.w = (uint)f2bf(s6 * rd) | ((uint)f2bf(s7 * rd) << 16);
            // mean -> chunk slot; h -> chunk 16+slot (XOR row swizzle)
            *(uint4*)&A[r * 256 + (slot ^ (r & 7)) * 8] = o4;
            *(uint4*)&A[r * 256 + ((16 + slot) ^ (r & 7)) * 8] = hv;
        }
    }
}

__global__ __launch_bounds__(1024, 8) void k_sage_f(
    const uint* __restrict__ hb, const int* __restrict__ cnt,
    const ushort* __restrict__ slots,
    const ushort* __restrict__ Wp, const float* __restrict__ bl,
    ushort* __restrict__ out_b) {
    __shared__ __align__(16) ushort A[64 * 256];
    const int t = threadIdx.x;
    const int w = t >> 6, lane = t & 63;
    const int node0 = blockIdx.x * 64;

    sage_gather_stage(A, hb, cnt, slots, node0, w, lane);
    __syncthreads();

    // MFMA: wave (wm = w>>2, wn = w&3) -> rows wm*16..+15, ch wn*32..+31
    const int wm = w >> 2, wn = w & 3;
    const int lg = lane >> 4, lr = lane & 15;
    ffrag acc[2];
    acc[0] = (ffrag)0.f;
    acc[1] = (ffrag)0.f;
#pragma unroll 2
    for (int ks = 0; ks < 8; ++ks) {
        int r = wm * 16 + lr;
        int c = ks * 4 + lg;
        bfrag a = *(const bfrag*)&A[r * 256 + (c ^ (r & 7)) * 8];
#pragma unroll
        for (int in = 0; in < 2; ++in) {
            int nf = wn * 2 + in;
            bfrag b = *(const bfrag*)&Wp[(((nf * 8) + ks) * 64 + lane) * 8];
            acc[in] = __builtin_amdgcn_mfma_f32_16x16x32_bf16(a, b, acc[in],
                                                              0, 0, 0);
        }
    }
#pragma unroll
    for (int in = 0; in < 2; ++in) {
        int ch = (wn * 2 + in) * 16 + lr;
        float bias = bl[ch];
#pragma unroll
        for (int rq = 0; rq < 4; ++rq) {
            int node = node0 + wm * 16 + lg * 4 + rq;
            if (node < N_NODES) {
                float v = acc[in][rq] + bias;
                v = (v > 0.f) ? v : 0.f;
                out_b[node * C + ch] = f2bf(v);
            }
        }
    }
}

// ---------------------------------------------------------------------------
// Fused last layer: gather + GEMM + final projection + log_softmax.
// Main stages as k_sage_f; h3 restaged to LDS (alias A); waves 0-3 run the
// K=128,N=64 second GEMM + per-node log_softmax (r9-verified mapping).
// ---------------------------------------------------------------------------

__global__ __launch_bounds__(1024, 8) void k_sage_fout(
    const uint* __restrict__ hb, const int* __restrict__ cnt,
    const ushort* __restrict__ slots,
    const ushort* __restrict__ Wp, const float* __restrict__ bl,
    const ushort* __restrict__ Wpl, const float* __restrict__ blin,
    float* __restrict__ out) {
    __shared__ __align__(16) ushort A[64 * 256];
    const int t = threadIdx.x;
    const int w = t >> 6, lane = t & 63;
    const int node0 = blockIdx.x * 64;

    sage_gather_stage(A, hb, cnt, slots, node0, w, lane);
    __syncthreads();

    const int wm = w >> 2, wn = w & 3;
    const int lg = lane >> 4, lr = lane & 15;
    ffrag acc[2];
    acc[0] = (ffrag)0.f;
    acc[1] = (ffrag)0.f;
#pragma unroll 2
    for (int ks = 0; ks < 8; ++ks) {
        int r = wm * 16 + lr;
        int c = ks * 4 + lg;
        bfrag a = *(const bfrag*)&A[r * 256 + (c ^ (r & 7)) * 8];
#pragma unroll
        for (int in = 0; in < 2; ++in) {
            int nf = wn * 2 + in;
            bfrag b = *(const bfrag*)&Wp[(((nf * 8) + ks) * 64 + lane) * 8];
            acc[in] = __builtin_amdgcn_mfma_f32_16x16x32_bf16(a, b, acc[in],
                                                              0, 0, 0);
        }
    }

    // h3 -> LDS (alias A; all reads of A completed)
    __syncthreads();
    ushort* H = A;          // [64 rows][128 bf16], chunk swizzle c ^ (row&7)
#pragma unroll
    for (int in = 0; in < 2; ++in) {
        int ch = (wn * 2 + in) * 16 + lr;
        float bias = bl[ch];
        int cfull = ch >> 3, cb = ch & 7;
#pragma unroll
        for (int rq = 0; rq < 4; ++rq) {
            int row = wm * 16 + lg * 4 + rq;
            float v = acc[in][rq] + bias;
            v = (v > 0.f) ? v : 0.f;
            H[row * 128 + (cfull ^ (row & 7)) * 8 + cb] = f2bf(v);
        }
    }
    __syncthreads();

    // second GEMM + log_softmax: waves 0-3 only (row-group = w)
    if (w < 4) {
        ffrag acc2[4];
#pragma unroll
        for (int in2 = 0; in2 < 4; ++in2) acc2[in2] = (ffrag)0.f;
#pragma unroll
        for (int ks = 0; ks < 4; ++ks) {
            int row = w * 16 + lr;
            int c2 = ks * 4 + lg;
            bfrag a2 = *(const bfrag*)&H[row * 128 + (c2 ^ (row & 7)) * 8];
#pragma unroll
            for (int in2 = 0; in2 < 4; ++in2) {
                bfrag b2 = *(const bfrag*)&Wpl[(((in2 * 4) + ks) * 64 + lane) * 8];
                acc2[in2] = __builtin_amdgcn_mfma_f32_16x16x32_bf16(
                    a2, b2, acc2[in2], 0, 0, 0);
            }
        }
        float bv0 = blin[lr], bv1 = blin[16 + lr], bv2 = blin[32 + lr],
              bv3 = blin[48 + lr];
#pragma unroll
        for (int rq = 0; rq < 4; ++rq) {
            int node = node0 + w * 16 + lg * 4 + rq;
            float L0 = acc2[0][rq] + bv0, L1 = acc2[1][rq] + bv1;
            float L2 = acc2[2][rq] + bv2, L3 = acc2[3][rq] + bv3;
            float m = fmaxf(fmaxf(L0, L1), fmaxf(L2, L3));
#pragma unroll
            for (int o = 1; o < 16; o <<= 1) m = fmaxf(m, __shfl_xor(m, o));
            float s = __expf(L0 - m) + __expf(L1 - m) + __expf(L2 - m) +
                      __expf(L3 - m);
#pragma unroll
            for (int o = 1; o < 16; o <<= 1) s += __shfl_xor(s, o);
            float ls = __logf(s) + m;
            if (node < N_NODES) {
                out[node * OUTC + lr]      = L0 - ls;
                out[node * OUTC + 16 + lr] = L1 - ls;
                out[node * OUTC + 32 + lr] = L2 - ls;
                out[node * OUTC + 48 + lr] = L3 - ls;
            }
        }
    }
}

// ---------------------------------------------------------------------------

extern "C" void kernel_launch(void* const* d_in, const int* in_sizes, int n_in,
                              void* d_out, int out_size, void* d_ws,
                              size_t ws_size, hipStream_t stream) {
    const float* x = (const float*)d_in[0];
    const int* ei = (const int*)d_in[1];
    const int* src = ei;
    const int* dst = ei + N_EDGES;
    const float* Wl0 = (const float*)d_in[2];
    const float* bl0 = (const float*)d_in[3];
    const float* Wr0 = (const float*)d_in[4];
    const float* Wl1 = (const float*)d_in[5];
    const float* bl1 = (const float*)d_in[6];
    const float* Wr1 = (const float*)d_in[7];
    const float* Wl2 = (const float*)d_in[8];
    const float* bl2 = (const float*)d_in[9];
    const float* Wr2 = (const float*)d_in[10];
    const float* Wlin = (const float*)d_in[11];
    const float* blin = (const float*)d_in[12];

    // workspace layout (all 16B-aligned)
    int* cnt = (int*)d_ws;                          // 50000 ints
    ushort* slots = (ushort*)(cnt + N_NODES);       // 50000*64 ushorts (6.4 MB)
    uint* xb = (uint*)(slots + (size_t)N_NODES * CAP);  // N*64 (12.8 MB)
    uint* bufA = xb + (size_t)N_NODES * 64;         // 12.8 MB
    uint* bufB = bufA + (size_t)N_NODES * 64;       // 12.8 MB
    ushort* wp = (ushort*)(bufB + (size_t)N_NODES * 64);  // 3*32768
    ushort* wpl = wp + 3 * 32768;                   // 8192

    hipMemsetAsync(cnt, 0, (size_t)N_NODES * sizeof(int), stream);

    k_prep_mega<<<FILLG_B + CAST_B + 3 * PREPW_B + WLIN_B, 256, 0, stream>>>(
        src, dst, cnt, slots, (const float4*)x, (uint4*)xb,
        Wl0, Wr0, Wl1, Wr1, Wl2, Wr2, Wlin, wp, wpl);

    const int MM_GRID = (N_NODES + 63) / 64;

    k_sage_f<<<MM_GRID, 1024, 0, stream>>>(xb, cnt, slots, wp, bl0,
                                           (ushort*)bufA);
    k_sage_f<<<MM_GRID, 1024, 0, stream>>>(bufA, cnt, slots, wp + 32768, bl1,
                                           (ushort*)bufB);
    k_sage_fout<<<MM_GRID, 1024, 0, stream>>>(bufB, cnt, slots, wp + 65536,
                                              bl2, wpl, blin, (float*)d_out);
}